// Round 4
// baseline (540.752 us; speedup 1.0000x reference)
//
#include <hip/hip_runtime.h>

// IndRNN recurrence: h_t = relu(h_{t-1} * w + x_t), elementwise over (B,H),
// sequential over T.
//
// R5: R2->R4 falsified the parallelism theory (8 -> 24-32 waves/CU: 501 ->
// 495 us; BW pinned at ~1.7 TB/s while fills hit 6.5). Diagnosis: pattern
// ceiling. Every walker visits a 1-4 KiB island then jumps 256 KiB (2^18
// stride -> same channel/bank set), so DRAM delivers ~256 B per row
// activate: 256 B x ~256 pseudochannels / 45 ns = ~1.5 TB/s = measured.
//
// Fix: contiguous fronts. One block (512 thr) owns a 128 KiB contiguous
// half-slab and walks its chunk's t in lockstep (__syncthreads per step).
// Thread owns R=16 lane-interleaved float4 sites (site k = k*512+tid): every
// load instruction is a dense 16 KiB region, the block's per-step front is
// 128 KiB contiguous, immune to inter-wave drift. A 16-deep per-thread load
// ring prefetches step t+1 during step t (step time ~5 us >> 1 us latency).
// Per-thread w collapses to one float4 (512 = 2*H4 aligned). DRAM sees 128
// dense streams advancing linearly through 2 MiB each = the m13 pattern.
//
// Math (exact, as R2/R4 which passed at absmax 0.25): relu(w*h+x) is
// max-affine in h; g(h)=max(A*h+B,C) composes A'=wA, B'=wB+x, C'=max(wC+x,0).
// C init 0 valid for h>=0. NC=64, TC=16, A=w^16.
//
// Traffic: P1 256rd+32wr; P2 ~48 MiB L3-hot; P3 272rd+256wr(nt) ~= 820 MiB.
// Predict 155-210 us at 4.5-6 TB/s. >=400 us kills the dense-front theory
// -> next round A/Bs read-pattern vs write-pattern in isolation.

#define T_DIM 1024
#define B_DIM 64
#define H_DIM 1024
#define BH    (B_DIM * H_DIM)     // 65536
#define BH4   (BH / 4)            // 16384 float4 per t-slab
#define H4    (H_DIM / 4)         // 256
#define NC    64                  // chunks over T
#define TC    (T_DIM / NC)        // 16 steps per chunk
#define R     16                  // float4 sites per thread
#define PTHR  512                 // threads per streaming block
#define HALF4 (PTHR * R)          // 8192 float4 = 128 KiB half-slab

typedef float v4f __attribute__((ext_vector_type(4)));

__device__ __forceinline__ float4 relu_step(float4 h, float4 wv, float4 xv) {
    float4 r;
    r.x = fmaxf(fmaf(h.x, wv.x, xv.x), 0.0f);
    r.y = fmaxf(fmaf(h.y, wv.y, xv.y), 0.0f);
    r.z = fmaxf(fmaf(h.z, wv.z, xv.z), 0.0f);
    r.w = fmaxf(fmaf(h.w, wv.w, xv.w), 0.0f);
    return r;
}

__device__ __forceinline__ void nt_store4(float4* p, float4 v) {
    __builtin_nontemporal_store(*reinterpret_cast<const v4f*>(&v),
                                reinterpret_cast<v4f*>(p));
}

// Pass 1: per-chunk composed (B, C). 128 blocks; block = (chunk, half-slab).
__global__ __launch_bounds__(PTHR, 2) void indrnn_compose(
    const float* __restrict__ x,
    const float* __restrict__ w,
    float* __restrict__ Bws,          // [NC][BH]
    float* __restrict__ Cws)          // [NC][BH]
{
    const int b    = blockIdx.x;      // 2*NC blocks
    const int c    = b >> 1;
    const int base = (b & 1) * HALF4;
    const int tid  = threadIdx.x;

    const float4 wv = reinterpret_cast<const float4*>(w)[tid & (H4 - 1)];
    const float4* xp = reinterpret_cast<const float4*>(x)
                     + (size_t)c * TC * BH4 + base + tid;

    float4 Bv[R], Cv[R], ring[R];
    #pragma unroll
    for (int k = 0; k < R; ++k) {
        Bv[k] = make_float4(0.f, 0.f, 0.f, 0.f);
        Cv[k] = make_float4(0.f, 0.f, 0.f, 0.f);
        ring[k] = xp[k * PTHR];
    }

    for (int t = 0; t < TC; ++t) {
        const size_t noff = (size_t)((t + 1 < TC) ? t + 1 : t) * BH4;
        #pragma unroll
        for (int k = 0; k < R; ++k) {
            const float4 xv = ring[k];
            ring[k] = xp[noff + k * PTHR];       // prefetch next step
            Bv[k].x = fmaf(Bv[k].x, wv.x, xv.x);
            Bv[k].y = fmaf(Bv[k].y, wv.y, xv.y);
            Bv[k].z = fmaf(Bv[k].z, wv.z, xv.z);
            Bv[k].w = fmaf(Bv[k].w, wv.w, xv.w);
            Cv[k] = relu_step(Cv[k], wv, xv);
        }
        __syncthreads();   // keep the block's 8 waves front-aligned
    }

    #pragma unroll
    for (int k = 0; k < R; ++k) {
        const size_t o = (size_t)c * BH4 + base + k * PTHR + tid;
        reinterpret_cast<float4*>(Bws)[o] = Bv[k];
        reinterpret_cast<float4*>(Cws)[o] = Cv[k];
    }
}

// Pass 2: serial scan over chunks -> exact chunk-start h for every chunk.
// 16K threads over 48 MiB L3-hot data. ~10 us.
__global__ __launch_bounds__(256) void indrnn_boundary(
    const float* __restrict__ w,
    const float* __restrict__ h0,
    const float* __restrict__ Bws,
    const float* __restrict__ Cws,
    float* __restrict__ Hstart)       // [NC][BH]
{
    const int i4 = blockIdx.x * 256 + threadIdx.x;   // BH4 threads
    const float4 wv = reinterpret_cast<const float4*>(w)[i4 & (H4 - 1)];

    // A = w^TC = w^16 via 4 squarings
    float4 A = wv;
    #pragma unroll
    for (int k = 0; k < 4; ++k) {
        A.x *= A.x; A.y *= A.y; A.z *= A.z; A.w *= A.w;
    }

    float4 h = reinterpret_cast<const float4*>(h0)[i4];
    for (int c = 0; c < NC; ++c) {
        reinterpret_cast<float4*>(Hstart)[(size_t)c * BH4 + i4] = h;
        const float4 Bv = reinterpret_cast<const float4*>(Bws)[(size_t)c * BH4 + i4];
        const float4 Cv = reinterpret_cast<const float4*>(Cws)[(size_t)c * BH4 + i4];
        h.x = fmaxf(fmaf(A.x, h.x, Bv.x), Cv.x);
        h.y = fmaxf(fmaf(A.y, h.y, Bv.y), Cv.y);
        h.z = fmaxf(fmaf(A.z, h.z, Bv.z), Cv.z);
        h.w = fmaxf(fmaf(A.w, h.w, Bv.w), Cv.w);
    }
}

// Pass 3: per-chunk recurrence from the exact chunk-start h. Same geometry
// and front structure as pass 1; nontemporal stores for out.
__global__ __launch_bounds__(PTHR, 2) void indrnn_run(
    const float* __restrict__ x,
    const float* __restrict__ w,
    const float* __restrict__ Hstart,
    float* __restrict__ out)
{
    const int b    = blockIdx.x;      // 2*NC blocks
    const int c    = b >> 1;
    const int base = (b & 1) * HALF4;
    const int tid  = threadIdx.x;

    const float4 wv = reinterpret_cast<const float4*>(w)[tid & (H4 - 1)];
    const float4* xp = reinterpret_cast<const float4*>(x)
                     + (size_t)c * TC * BH4 + base + tid;
    float4*       op = reinterpret_cast<float4*>(out)
                     + (size_t)c * TC * BH4 + base + tid;

    float4 h[R], ring[R];
    #pragma unroll
    for (int k = 0; k < R; ++k) {
        h[k] = reinterpret_cast<const float4*>(Hstart)
                   [(size_t)c * BH4 + base + k * PTHR + tid];
        ring[k] = xp[k * PTHR];
    }

    for (int t = 0; t < TC; ++t) {
        const size_t noff = (size_t)((t + 1 < TC) ? t + 1 : t) * BH4;
        const size_t ooff = (size_t)t * BH4;
        #pragma unroll
        for (int k = 0; k < R; ++k) {
            const float4 xv = ring[k];
            ring[k] = xp[noff + k * PTHR];       // prefetch next step
            h[k] = relu_step(h[k], wv, xv);
            nt_store4(op + ooff + k * PTHR, h[k]);
        }
        __syncthreads();   // keep the block's 8 waves front-aligned
    }
}

extern "C" void kernel_launch(void* const* d_in, const int* in_sizes, int n_in,
                              void* d_out, int out_size, void* d_ws, size_t ws_size,
                              hipStream_t stream) {
    const float* x  = (const float*)d_in[0];
    const float* w  = (const float*)d_in[1];
    const float* h0 = (const float*)d_in[2];
    float* out = (float*)d_out;

    // workspace: Bws + Cws + Hstart, each [NC][BH] floats (16 MiB) = 48 MiB
    float* Bws    = (float*)d_ws;
    float* Cws    = Bws + (size_t)NC * BH;
    float* Hstart = Cws + (size_t)NC * BH;

    indrnn_compose <<<2 * NC,    PTHR, 0, stream>>>(x, w, Bws, Cws);
    indrnn_boundary<<<BH4 / 256, 256,  0, stream>>>(w, h0, Bws, Cws, Hstart);
    indrnn_run     <<<2 * NC,    PTHR, 0, stream>>>(x, w, Hstart, out);
}